// Round 1
// 64.185 us; speedup vs baseline: 1.0265x; 1.0265x over previous
//
#include <hip/hip_runtime.h>
#include <math.h>

#define NB 32
#define NA 48
#define RCRf 5.2f
#define RCAf 3.5f
#define PI_F 3.14159265358979f
#define CMAX 1000   // triples per chunk; 1 chunk unless m >= 46 (T > 1000)

typedef unsigned short ushort_t;
typedef __fp16 h2f __attribute__((ext_vector_type(2)));
static __device__ __forceinline__ unsigned pkh(float a, float b) {
    h2f v = __builtin_amdgcn_cvt_pkrtz(a, b);
    return __builtin_bit_cast(unsigned, v);
}
static __device__ __forceinline__ float uph(ushort_t u) {
    return (float)__builtin_bit_cast(__fp16, u);
}

// closed-form triangular decode: t -> (jj<kk) among m compacted neighbors
static __device__ __forceinline__ void tri_decode(int t, int m, int T, int& jj, int& kk) {
    const int u = T - 1 - t;
    int r = (int)((__builtin_amdgcn_sqrtf(8.0f * (float)u + 1.0f) - 1.0f) * 0.5f);
    while (r * (r + 1) / 2 > u) --r;
    while ((r + 1) * (r + 2) / 2 <= u) ++r;
    jj = m - 2 - r;
    kk = m - 1 - (u - r * (r + 1) / 2);
}

// One block per (batch, center atom). 320 threads = 5 waves, 6 blocks/CU,
// all 1536 blocks co-resident in ONE round (LDS ~26.3 KB <= 163840/6).
//
// R6: species-SORTED ballot compaction => bucket counts/bases are closed-form
// from 4 popcounts, and each triple's p-sorted scatter slot is closed-form
// (jl*n2+kl, triangular on diagonal). Deletes: histogram pass over T triples,
// ~2T+10 LDS atomics, the 10-bucket prefix phase, and 2 of 4 barriers.
__global__ __launch_bounds__(320)
void aev_kernel(const int* __restrict__ species, const float* __restrict__ coords,
                float* __restrict__ out)
{
    const int bid = blockIdx.x;
    const int b = bid / NA;
    const int i = bid - b * NA;
    const int tid = threadIdx.x;

    __shared__ float pd[NA], pfr[NA];
    __shared__ int   ssp[NA];
    __shared__ __align__(16) float4 cpk[NA];   // (dx,dy,dz,d), species-sorted RCA neighbors
    __shared__ float cfc[NA];
    __shared__ float radpart[5 * 64];
    __shared__ __align__(16) ushort_t f1h[CMAX * 8];   // fp16 f1[z], 16 B/triple
    __shared__ __align__(16) ushort_t w2h[CMAX * 4];   // fp16 w*f2[a], 8 B/triple
    __shared__ int shb[11];    // bucket bases (exclusive prefix), shb[10] = T
    __shared__ int shn[4];     // per-species compacted counts
    __shared__ int shs[3];     // segment starts n0, n0+n1, n0+n1+n2

    // ---- wave 0: global load + pair pass + species-sorted ballot compaction ----
    if (tid < 64) {
        const int j = tid;
        float dx = 0.f, dy = 0.f, dz = 0.f, d = 1.0f, fr = 0.0f, fa = 0.0f;
        int sj = 0;
        bool inA = false;
        if (j < NA) {
            const float* cb = coords + (size_t)b * NA * 3;
            const float xi = cb[3 * i], yi = cb[3 * i + 1], zi = cb[3 * i + 2];
            dx = cb[3 * j] - xi; dy = cb[3 * j + 1] - yi; dz = cb[3 * j + 2] - zi;
            d = sqrtf(dx * dx + dy * dy + dz * dz);
            sj = species[b * NA + j];
            if (j != i && d <= RCRf) fr = 0.5f * __cosf((PI_F / RCRf) * d) + 0.5f;
            if (j != i && d <= RCAf) { inA = true; fa = 0.5f * __cosf((PI_F / RCAf) * d) + 0.5f; }
            pd[j] = d; pfr[j] = fr; ssp[j] = sj;
        }
        const unsigned long long mk0 = __ballot(inA && sj == 0);
        const unsigned long long mk1 = __ballot(inA && sj == 1);
        const unsigned long long mk2 = __ballot(inA && sj == 2);
        const unsigned long long mk3 = __ballot(inA && sj == 3);
        const int n0 = (int)__popcll(mk0), n1 = (int)__popcll(mk1);
        const int n2 = (int)__popcll(mk2), n3 = (int)__popcll(mk3);
        if (inA) {
            const unsigned long long below = (1ull << j) - 1ull;
            int pos;
            if (sj == 0)      pos = (int)__popcll(mk0 & below);
            else if (sj == 1) pos = n0 + (int)__popcll(mk1 & below);
            else if (sj == 2) pos = n0 + n1 + (int)__popcll(mk2 & below);
            else              pos = n0 + n1 + n2 + (int)__popcll(mk3 & below);
            cpk[pos] = make_float4(dx, dy, dz, d);
            cfc[pos] = fa;
        }
        if (j == 0) {
            shn[0] = n0; shn[1] = n1; shn[2] = n2; shn[3] = n3;
            shs[0] = n0; shs[1] = n0 + n1; shs[2] = n0 + n1 + n2;
            const int c[10] = { n0*(n0-1)/2, n0*n1, n0*n2, n0*n3,
                                n1*(n1-1)/2, n1*n2, n1*n3,
                                n2*(n2-1)/2, n2*n3, n3*(n3-1)/2 };
            int run = 0;
            #pragma unroll
            for (int p = 0; p < 10; ++p) { shb[p] = run; run += c[p]; }
            shb[10] = run;   // == T
        }
    }
    __syncthreads();                                                  // S1

    const int n0c = shn[0], n1c = shn[1], n2c = shn[2], n3c = shn[3];
    const int m = n0c + n1c + n2c + n3c;
    const int T = m * (m - 1) / 2;
    const int ss1 = shs[0], ss2 = shs[1], ss3 = shs[2];

    // ---- radial partials (broadcast LDS reads, register acc) ----
    {
        const int f = tid & 63, seg = tid >> 6;
        const int s = f >> 4, r = f & 15;
        const float shf = 0.9f + 0.26875f * (float)r;
        float acc = 0.0f;
        const int j0 = seg * 10, j1 = min(NA, j0 + 10);
        for (int j = j0; j < j1; ++j) {
            const float fr = pfr[j];
            if (fr != 0.0f) {
                const float u = pd[j] - shf;
                const float v = 0.25f * __expf(-16.0f * u * u) * fr;
                acc += (ssp[j] == s) ? v : 0.0f;
            }
        }
        radpart[seg * 64 + f] = acc;
    }

    const int pmine = tid >> 5, amine = (tid >> 3) & 3, zmine = tid & 7;
    const int mybase = shb[pmine];
    const int myend  = shb[pmine + 1];
    const float CZ[8] = { 0.98078528f, 0.83146961f, 0.55557023f, 0.19509032f,
                         -0.19509032f,-0.55557023f,-0.83146961f,-0.98078528f };
    const float SZ[8] = { 0.19509032f, 0.55557023f, 0.83146961f, 0.98078528f,
                          0.98078528f, 0.83146961f, 0.55557023f, 0.19509032f };
    const float SA[4] = { 0.9f, 1.55f, 2.2f, 2.85f };
    float acc_a = 0.0f;

    const int nchunks = max(1, (T + CMAX - 1) / CMAX);   // ==1 unless m>=46

    for (int c = 0; c < nchunks; ++c) {
        if (c) __syncthreads();   // protect f1h/w2h from previous consume
        const int lo = c * CMAX;
        const int hi = min(T, lo + CMAX);

        // produce: closed-form p-sorted slot, fp16 records, NO atomics
        for (int t = tid; t < T; t += 320) {
            int jj, kk; tri_decode(t, m, T, jj, kk);
            // sorted compaction => s1 <= s2 always
            const int s1 = (jj >= ss1) + (jj >= ss2) + (jj >= ss3);
            const int s2 = (kk >= ss1) + (kk >= ss2) + (kk >= ss3);
            const int p  = (s1 * (9 - s1)) / 2 + (s2 - s1);
            const int sb1 = s1 == 0 ? 0 : (s1 == 1 ? ss1 : (s1 == 2 ? ss2 : ss3));
            const int sb2 = s2 == 0 ? 0 : (s2 == 1 ? ss1 : (s2 == 2 ? ss2 : ss3));
            const int ns2 = s2 == 0 ? n0c : (s2 == 1 ? n1c : (s2 == 2 ? n2c : n3c));
            const int jl = jj - sb1, kl = kk - sb2;
            const int idx = (s1 == s2) ? ((jl * (2 * ns2 - jl - 1)) / 2 + (kl - jl - 1))
                                       : (jl * ns2 + kl);
            const int pos = shb[p] + idx;
            if (pos >= lo && pos < hi) {
                const float4 qj = cpk[jj];      // ds_read_b128
                const float4 qk = cpk[kk];      // ds_read_b128
                const float dot = qj.x * qk.x + qj.y * qk.y + qj.z * qk.z;
                const float cosT = 0.95f * dot * __builtin_amdgcn_rcpf(qj.w * qk.w);
                const float sinT = __builtin_amdgcn_sqrtf(fmaxf(1.0f - cosT * cosT, 0.0f));
                const float avg = 0.5f * (qj.w + qk.w);
                const float w = 2.0f * cfc[jj] * cfc[kk];

                float f1v[8];
                #pragma unroll
                for (int z = 0; z < 8; ++z) {
                    const float base = 0.5f + 0.5f * (cosT * CZ[z] + sinT * SZ[z]);
                    const float b2 = base * base, b4 = b2 * b2, b8 = b4 * b4, b16 = b8 * b8;
                    f1v[z] = b16 * b16;   // base^32
                }
                float w2v[4];
                #pragma unroll
                for (int a = 0; a < 4; ++a) {
                    const float u = avg - SA[a];
                    w2v[a] = w * __expf(-8.0f * u * u);
                }
                const int wp = pos - lo;
                uint4 rf;
                rf.x = pkh(f1v[0], f1v[1]); rf.y = pkh(f1v[2], f1v[3]);
                rf.z = pkh(f1v[4], f1v[5]); rf.w = pkh(f1v[6], f1v[7]);
                ((uint4*)f1h)[wp] = rf;                       // ds_write_b128
                uint2 rw;
                rw.x = pkh(w2v[0], w2v[1]); rw.y = pkh(w2v[2], w2v[3]);
                ((uint2*)w2h)[wp] = rw;                       // ds_write_b64
            }
        }
        __syncthreads();                                              // S2

        // consume: thread owns (p,a,z), scans its p-bucket (2 u16 reads + fma)
        const int k0 = max(mybase, lo), k1 = min(myend, hi);
        for (int k = k0; k < k1; ++k)
            acc_a += uph(w2h[(k - lo) * 4 + amine]) * uph(f1h[(k - lo) * 8 + zmine]);
    }

    // ---- output (radpart fenced by S2) ----
    float* op = out + NB * NA + (size_t)(b * NA + i) * 384;
    if (tid < 64) {
        op[tid] = radpart[tid] + radpart[64 + tid] + radpart[128 + tid] +
                  radpart[192 + tid] + radpart[256 + tid];
    }
    op[64 + tid] = acc_a;
    if (tid == 0) out[b * NA + i] = (float)ssp[i];
}

extern "C" void kernel_launch(void* const* d_in, const int* in_sizes, int n_in,
                              void* d_out, int out_size, void* d_ws, size_t ws_size,
                              hipStream_t stream) {
    const int*   species = (const int*)d_in[0];
    const float* coords  = (const float*)d_in[1];
    float*       out     = (float*)d_out;
    aev_kernel<<<NB * NA, 320, 0, stream>>>(species, coords, out);
}